// Round 4
// baseline (106.713 us; speedup 1.0000x reference)
//
#include <hip/hip_runtime.h>

// Problem constants (from reference)
constexpr int B_  = 16;
constexpr int NV_ = 10475;
constexpr int F_  = 20908;
constexpr int P_  = F_ * 8;              // 167264 pairs per batch (= 8 * F_)
constexpr int BF_ = B_ * F_;             // 334528 (b,face) records
constexpr float LINEAR_MAX_ = 1000.0f;

// d_ws layout:
//   cnd   : float4[BF_]      at byte offset 0            {n.x, n.y, n.z, dot(c,n)}
//   verts : float4[BF_ * 3]  at byte offset BF_*16       {v0,v1,v2 packed, 48B/record}
// total = BF_*64 = 21,409,792 bytes (d_ws is ~256 MB per harness fill size).

__global__ __launch_bounds__(256) void face_precompute_kernel(
    const float* __restrict__ v,        // (B, NV, 3) f32
    const int*   __restrict__ faces,    // (F, 3) i32
    float4*      __restrict__ cnd,      // (B*F) {n, c·n}
    float4*      __restrict__ verts)    // (B*F, 3) packed vertices
{
    const int f = blockIdx.x * blockDim.x + threadIdx.x;
    const int b = blockIdx.y;
    if (f >= F_) return;

    const float* __restrict__ vb = v + (size_t)b * (NV_ * 3);
    const int i0 = faces[f * 3 + 0] * 3;
    const int i1 = faces[f * 3 + 1] * 3;
    const int i2 = faces[f * 3 + 2] * 3;

    const float v0x = vb[i0 + 0], v0y = vb[i0 + 1], v0z = vb[i0 + 2];
    const float v1x = vb[i1 + 0], v1y = vb[i1 + 1], v1z = vb[i1 + 2];
    const float v2x = vb[i2 + 0], v2y = vb[i2 + 1], v2z = vb[i2 + 2];

    const float third = 1.0f / 3.0f;
    const float cx = (v0x + v1x + v2x) * third;
    const float cy = (v0y + v1y + v2y) * third;
    const float cz = (v0z + v1z + v2z) * third;

    const float e1x = v1x - v0x, e1y = v1y - v0y, e1z = v1z - v0z;
    const float e2x = v2x - v0x, e2y = v2y - v0y, e2z = v2z - v0z;
    float nx = e1y * e2z - e1z * e2y;
    float ny = e1z * e2x - e1x * e2z;
    float nz = e1x * e2y - e1y * e2x;
    const float inv = 1.0f / (sqrtf(nx * nx + ny * ny + nz * nz) + 1e-12f);
    nx *= inv; ny *= inv; nz *= inv;

    const int bf = b * F_ + f;
    cnd[bf] = make_float4(nx, ny, nz, cx * nx + cy * ny + cz * nz);
    verts[bf * 3 + 0] = make_float4(v0x, v0y, v0z, v1x);
    verts[bf * 3 + 1] = make_float4(v1y, v1z, v2x, v2y);
    verts[bf * 3 + 2] = make_float4(v2z, 0.0f, 0.0f, 0.0f);
}

// One thread handles 8 pairs strided by F_ (P_ == 8*F_): coalesced int2 loads.
// Branchless: invalid pairs clamp to record 0 of batch b -> L1-broadcast, free.
__global__ __launch_bounds__(256) void pen_pairs_kernel(
    const int2*  __restrict__ coll,     // (B, P) pairs
    const float4* __restrict__ cnd,
    const float4* __restrict__ verts,
    float*       __restrict__ out)      // (B,)
{
    const int p = blockIdx.x * blockDim.x + threadIdx.x;
    const int b = blockIdx.y;

    float psi2 = 0.0f;

    if (p < F_) {
        const int2* __restrict__ cb = coll + (size_t)b * P_ + p;
        const int bofs = b * F_;

        #pragma unroll
        for (int k = 0; k < 8; ++k) {
            const int2 pr = cb[k * F_];
            const float m = ((pr.x | pr.y) >= 0) ? 1.0f : 0.0f;
            const int fR = bofs + ((pr.y > 0) ? pr.y : 0);   // receiver
            const int fI = bofs + ((pr.x > 0) ? pr.x : 0);   // intruder

            const float4 nd = cnd[fR];
            const float4 L0 = verts[fI * 3 + 0];
            const float4 L1 = verts[fI * 3 + 1];
            const float4 L2 = verts[fI * 3 + 2];

            float s = 0.0f;
            float t0 = nd.w - (L0.x * nd.x + L0.y * nd.y + L0.z * nd.z);
            t0 = fminf(fmaxf(t0, 0.0f), LINEAR_MAX_);
            s = fmaf(t0, t0, s);
            float t1 = nd.w - (L0.w * nd.x + L1.x * nd.y + L1.y * nd.z);
            t1 = fminf(fmaxf(t1, 0.0f), LINEAR_MAX_);
            s = fmaf(t1, t1, s);
            float t2 = nd.w - (L1.z * nd.x + L1.w * nd.y + L2.x * nd.z);
            t2 = fminf(fmaxf(t2, 0.0f), LINEAR_MAX_);
            s = fmaf(t2, t2, s);

            psi2 = fmaf(m, s, psi2);
        }
    }

    // ---- reduction: wave64 shfl -> LDS across waves -> one atomic/block ----
    #pragma unroll
    for (int off = 32; off > 0; off >>= 1)
        psi2 += __shfl_down(psi2, off, 64);

    __shared__ float wsum[4];   // 256 threads = 4 waves
    const int lane = threadIdx.x & 63;
    const int wid  = threadIdx.x >> 6;
    if (lane == 0) wsum[wid] = psi2;
    __syncthreads();

    if (threadIdx.x == 0) {
        const float blocksum = wsum[0] + wsum[1] + wsum[2] + wsum[3];
        atomicAdd(&out[b], blocksum);
    }
}

extern "C" void kernel_launch(void* const* d_in, const int* in_sizes, int n_in,
                              void* d_out, int out_size, void* d_ws, size_t ws_size,
                              hipStream_t stream) {
    const float* v     = (const float*)d_in[0];
    const int*   faces = (const int*)d_in[1];
    const int2*  coll  = (const int2*)d_in[2];
    float* out = (float*)d_out;

    float4* cnd   = (float4*)d_ws;
    float4* verts = (float4*)((char*)d_ws + (size_t)BF_ * sizeof(float4));

    // Harness poisons d_out to 0xAA before every timed launch — zero it here.
    hipMemsetAsync(out, 0, out_size * sizeof(float), stream);

    dim3 block(256);
    dim3 gridA((F_ + 255) / 256, B_);
    face_precompute_kernel<<<gridA, block, 0, stream>>>(v, faces, cnd, verts);

    dim3 gridB((F_ + 255) / 256, B_);   // each thread does 8 pairs
    pen_pairs_kernel<<<gridB, block, 0, stream>>>(coll, cnd, verts, out);
}

// Round 6
// 101.352 us; speedup vs baseline: 1.0529x; 1.0529x over previous
//
#include <hip/hip_runtime.h>

// Problem constants (from reference)
constexpr int B_  = 16;
constexpr int NV_ = 10475;
constexpr int F_  = 20908;
constexpr int P_  = F_ * 8;              // 167264 pairs per batch (= 8 * F_)
constexpr int BF_ = B_ * F_;             // 334528 (b,face) records
constexpr float LINEAR_MAX_ = 1000.0f;

// d_ws layout (total ~8.4 MB << ws_size):
//   cnd    : float4[BF_]       {n.x, n.y, n.z, dot(c,n)}     5.35 MB
//   vpack  : float4[B_*NV_]    {x, y, z, 0}                  2.68 MB
//   faces4 : int4[F_]          {i0, i1, i2, 0}               0.33 MB

// XCD b-locality swizzle: dispatcher assigns consecutive linear block ids
// round-robin across the 8 XCDs (heuristic). Map bid -> (b, px) so that each
// XCD services exactly 2 batches => per-XCD gather working set ~1.3 MB (L2-fit).
__device__ __forceinline__ void swz(int bid, int& b, int& px) {
    const int xcd = bid & 7;
    const int j   = bid >> 3;
    b  = xcd + ((j & 1) << 3);
    px = j >> 1;
}

// Pass 1: pack vertices to float4 (per b, same XCD that will read them) and
// faces rows to int4 (coalesced, shared).
__global__ __launch_bounds__(256) void pre_pack_kernel(
    const float* __restrict__ v,        // (B, NV, 3)
    const int*   __restrict__ faces,    // (F, 3)
    float4*      __restrict__ vpack,    // (B, NV)
    int4*        __restrict__ faces4)   // (F)
{
    const int bid = blockIdx.x;
    int b, px; swz(bid, b, px);
    const int t = threadIdx.x;

    const int g = bid * 256 + t;                 // linear, coalesced
    if (g < F_)
        faces4[g] = make_int4(faces[g*3+0], faces[g*3+1], faces[g*3+2], 0);

    const int vid = px * 256 + t;
    if (vid < NV_) {
        const float* src = v + ((size_t)b * NV_ + vid) * 3;
        vpack[b * NV_ + vid] = make_float4(src[0], src[1], src[2], 0.0f);
    }
}

// Pass 2: per (b,f) receiver record {n, c·n}.
__global__ __launch_bounds__(256) void face_cnd_kernel(
    const float4* __restrict__ vpack,
    const int4*   __restrict__ faces4,
    float4*       __restrict__ cnd)     // (B, F)
{
    const int bid = blockIdx.x;
    int b, px; swz(bid, b, px);
    const int f = px * 256 + threadIdx.x;
    if (f >= F_) return;

    const int4 fi = faces4[f];
    const float4* vb = vpack + (size_t)b * NV_;
    const float4 p0 = vb[fi.x];
    const float4 p1 = vb[fi.y];
    const float4 p2 = vb[fi.z];

    const float third = 1.0f / 3.0f;
    const float cx = (p0.x + p1.x + p2.x) * third;
    const float cy = (p0.y + p1.y + p2.y) * third;
    const float cz = (p0.z + p1.z + p2.z) * third;

    const float e1x = p1.x - p0.x, e1y = p1.y - p0.y, e1z = p1.z - p0.z;
    const float e2x = p2.x - p0.x, e2y = p2.y - p0.y, e2z = p2.z - p0.z;
    float nx = e1y * e2z - e1z * e2y;
    float ny = e1z * e2x - e1x * e2z;
    float nz = e1x * e2y - e1y * e2x;
    const float inv = 1.0f / (sqrtf(nx * nx + ny * ny + nz * nz) + 1e-12f);
    nx *= inv; ny *= inv; nz *= inv;

    cnd[b * F_ + f] = make_float4(nx, ny, nz, cx * nx + cy * ny + cz * nz);
}

// Pass 3: pairs. Per pair: 1 coalesced int2 + 5 scattered vector gathers
// (cnd, faces4, 3x vpack), all within the XCD-local ~1.3 MB working set.
__global__ __launch_bounds__(256) void pen_pairs_kernel(
    const int2*   __restrict__ coll,    // (B, P)
    const float4* __restrict__ cnd,
    const float4* __restrict__ vpack,
    const int4*   __restrict__ faces4,
    float*        __restrict__ out)     // (B,)
{
    const int bid = blockIdx.x;
    int b, px; swz(bid, b, px);
    const int p = px * 256 + threadIdx.x;

    float psi2 = 0.0f;

    if (p < F_) {
        const int2* __restrict__ cb = coll + (size_t)b * P_ + p;
        const float4* __restrict__ vb = vpack + (size_t)b * NV_;
        const float4* __restrict__ cb_cnd = cnd + (size_t)b * F_;

        #pragma unroll
        for (int k = 0; k < 8; ++k) {
            const int2 pr = cb[k * F_];
            const float m = ((pr.x | pr.y) >= 0) ? 1.0f : 0.0f;
            const int fR = (pr.y > 0) ? pr.y : 0;   // receiver
            const int fI = (pr.x > 0) ? pr.x : 0;   // intruder

            const float4 nd = cb_cnd[fR];
            const int4   fi = faces4[fI];
            const float4 a0 = vb[fi.x];
            const float4 a1 = vb[fi.y];
            const float4 a2 = vb[fi.z];

            float s = 0.0f;
            float t0 = nd.w - (a0.x * nd.x + a0.y * nd.y + a0.z * nd.z);
            t0 = fminf(fmaxf(t0, 0.0f), LINEAR_MAX_);
            s = fmaf(t0, t0, s);
            float t1 = nd.w - (a1.x * nd.x + a1.y * nd.y + a1.z * nd.z);
            t1 = fminf(fmaxf(t1, 0.0f), LINEAR_MAX_);
            s = fmaf(t1, t1, s);
            float t2 = nd.w - (a2.x * nd.x + a2.y * nd.y + a2.z * nd.z);
            t2 = fminf(fmaxf(t2, 0.0f), LINEAR_MAX_);
            s = fmaf(t2, t2, s);

            psi2 = fmaf(m, s, psi2);
        }
    }

    // ---- reduction: wave64 shfl -> LDS across waves -> one atomic/block ----
    #pragma unroll
    for (int off = 32; off > 0; off >>= 1)
        psi2 += __shfl_down(psi2, off, 64);

    __shared__ float wsum[4];   // 256 threads = 4 waves
    const int lane = threadIdx.x & 63;
    const int wid  = threadIdx.x >> 6;
    if (lane == 0) wsum[wid] = psi2;
    __syncthreads();

    if (threadIdx.x == 0) {
        const float blocksum = wsum[0] + wsum[1] + wsum[2] + wsum[3];
        atomicAdd(&out[b], blocksum);
    }
}

extern "C" void kernel_launch(void* const* d_in, const int* in_sizes, int n_in,
                              void* d_out, int out_size, void* d_ws, size_t ws_size,
                              hipStream_t stream) {
    const float* v     = (const float*)d_in[0];
    const int*   faces = (const int*)d_in[1];
    const int2*  coll  = (const int2*)d_in[2];
    float* out = (float*)d_out;

    char* ws = (char*)d_ws;
    float4* cnd    = (float4*)ws;                                  ws += (size_t)BF_ * 16;
    float4* vpack  = (float4*)ws;                                  ws += (size_t)B_ * NV_ * 16;
    int4*   faces4 = (int4*)ws;

    // Harness poisons d_out to 0xAA before every timed launch — zero it here.
    hipMemsetAsync(out, 0, out_size * sizeof(float), stream);

    dim3 block(256);
    // vpack: 41 px-blocks per b * 16 b = 656 (also covers faces4 via linear id)
    pre_pack_kernel<<<dim3(656), block, 0, stream>>>(v, faces, vpack, faces4);
    // cnd / pairs: 82 px-blocks per b * 16 b = 1312
    face_cnd_kernel<<<dim3(1312), block, 0, stream>>>(vpack, faces4, cnd);
    pen_pairs_kernel<<<dim3(1312), block, 0, stream>>>(coll, cnd, vpack, faces4, out);
}